// Round 2
// baseline (280.840 us; speedup 1.0000x reference)
//
#include <hip/hip_runtime.h>
#include <hip/hip_bf16.h>
#include <stdint.h>

// MultiGraphConvLayer: H=3 heads, L=2 layers, B=16, S=512, D=512.
// bf16 MFMA (16x16x32) GEMMs, fp32 accumulate.
// Round 2: 2-phase prefetch (T3-min), k-major conflict-free LDS, T1 XCD swizzle.

#define HH 3
#define LL 2
#define BB 16
#define SS 512
#define DD 512
#define FF 3072  // HH*LL*DD

typedef __attribute__((ext_vector_type(8))) short bf16x8;
typedef __attribute__((ext_vector_type(4))) float f32x4;
typedef __attribute__((ext_vector_type(4))) float vfloat4;

__device__ __forceinline__ short f2b(float x) {
  union { float f; uint32_t u; } v; v.f = x;
  return (short)((v.u + 0x7FFFu + ((v.u >> 16) & 1u)) >> 16);
}
__device__ __forceinline__ float b2f(short s) {
  union { uint32_t u; float f; } v; v.u = ((uint32_t)(uint16_t)s) << 16;
  return v.f;
}

__device__ __forceinline__ void gld16(const short* g, short* l) {
  __builtin_amdgcn_global_load_lds((const __attribute__((address_space(1))) void*)g,
                                   (__attribute__((address_space(3))) void*)l, 16, 0, 0);
}

// T1: XCD-chunked blockIdx swizzle (grid must be divisible by 8 — all ours are).
__device__ __forceinline__ int xswz(int grid) {
  int cpx = grid >> 3;
  return (blockIdx.x & 7) * cpx + (blockIdx.x >> 3);
}

// ---- adj fp32 -> bf16, plus rdenom = 1/(rowsum+1). One wave per row of 512.
__global__ void k_cvt_adj(const float* __restrict__ adj, short* __restrict__ adjb,
                          float* __restrict__ rden) {
  int row = blockIdx.x * 4 + (threadIdx.x >> 6);
  int lane = threadIdx.x & 63;
  const float* src = adj + (size_t)row * SS;
  vfloat4 a = *(const vfloat4*)(src + lane * 8);
  vfloat4 b = *(const vfloat4*)(src + lane * 8 + 4);
  bf16x8 o;
  o[0] = f2b(a[0]); o[1] = f2b(a[1]); o[2] = f2b(a[2]); o[3] = f2b(a[3]);
  o[4] = f2b(b[0]); o[5] = f2b(b[1]); o[6] = f2b(b[2]); o[7] = f2b(b[3]);
  *(bf16x8*)(adjb + (size_t)row * SS + lane * 8) = o;
  float s = a[0]+a[1]+a[2]+a[3]+b[0]+b[1]+b[2]+b[3];
  #pragma unroll
  for (int off = 32; off > 0; off >>= 1) s += __shfl_xor(s, off);
  if (lane == 0) rden[row] = 1.0f / (s + 1.0f);
}

// ---- W_gcn and W_out fp32 -> bf16 (both are 1,572,864 elements).
__global__ void k_cvt_w(const float* __restrict__ wg, const float* __restrict__ wo,
                        short* __restrict__ wgb, short* __restrict__ wob) {
  size_t i = ((size_t)blockIdx.x * 256 + threadIdx.x) * 8;
  vfloat4 a = *(const vfloat4*)(wg + i);
  vfloat4 b = *(const vfloat4*)(wg + i + 4);
  bf16x8 o;
  o[0]=f2b(a[0]); o[1]=f2b(a[1]); o[2]=f2b(a[2]); o[3]=f2b(a[3]);
  o[4]=f2b(b[0]); o[5]=f2b(b[1]); o[6]=f2b(b[2]); o[7]=f2b(b[3]);
  *(bf16x8*)(wgb + i) = o;
  a = *(const vfloat4*)(wo + i);
  b = *(const vfloat4*)(wo + i + 4);
  o[0]=f2b(a[0]); o[1]=f2b(a[1]); o[2]=f2b(a[2]); o[3]=f2b(a[3]);
  o[4]=f2b(b[0]); o[5]=f2b(b[1]); o[6]=f2b(b[2]); o[7]=f2b(b[3]);
  *(bf16x8*)(wob + i) = o;
}

// ---- gcn_inputs [B][S][D] fp32 -> X0T [B][D][S] bf16 (64x64 LDS tile transpose)
__global__ void k_t_x0(const float* __restrict__ x, short* __restrict__ xt) {
  __shared__ short t[64][72];
  int bid = blockIdx.x;            // BB*64
  int b = bid >> 6, q = bid & 63;
  int s0 = (q >> 3) * 64, d0 = (q & 7) * 64;
  int tid = threadIdx.x;
  int r = tid >> 4, c4 = (tid & 15) * 4;
  const float* src = x + ((size_t)b * SS + s0) * DD + d0;
  #pragma unroll
  for (int rr = 0; rr < 64; rr += 16) {
    vfloat4 v = *(const vfloat4*)(src + (size_t)(r + rr) * DD + c4);
    t[r+rr][c4+0] = f2b(v[0]); t[r+rr][c4+1] = f2b(v[1]);
    t[r+rr][c4+2] = f2b(v[2]); t[r+rr][c4+3] = f2b(v[3]);
  }
  __syncthreads();
  int dloc = tid >> 3, s8 = (tid & 7) * 8;
  short* dst = xt + (size_t)b * DD * SS + s0;
  #pragma unroll
  for (int dd = 0; dd < 64; dd += 32) {
    bf16x8 o;
    #pragma unroll
    for (int j = 0; j < 8; j++) o[j] = t[s8 + j][dloc + dd];
    *(bf16x8*)(dst + (size_t)(d0 + dloc + dd) * SS + s8) = o;
  }
}

// ---- final slab (layer-0 outputs, bf16, row stride FF) -> YT [H*B][D][S] bf16
__global__ void k_t_y(const short* __restrict__ fin, short* __restrict__ yt) {
  __shared__ short t[64][72];
  int bid = blockIdx.x;            // HH*BB*64
  int hb = bid >> 6, q = bid & 63;
  int h = hb / BB, b = hb % BB;
  int s0 = (q >> 3) * 64, e0 = (q & 7) * 64;
  int tid = threadIdx.x;
  int r = tid >> 3, c8 = (tid & 7) * 8;
  const short* src = fin + ((size_t)b * SS + s0) * FF + (size_t)(h * LL) * DD + e0;
  #pragma unroll
  for (int rr = 0; rr < 64; rr += 32) {
    bf16x8 v = *(const bf16x8*)(src + (size_t)(r + rr) * FF + c8);
    #pragma unroll
    for (int j = 0; j < 8; j++) t[r+rr][c8+j] = v[j];
  }
  __syncthreads();
  int eloc = tid >> 3, s8 = (tid & 7) * 8;
  short* dst = yt + (size_t)hb * DD * SS + s0;
  #pragma unroll
  for (int ee = 0; ee < 64; ee += 32) {
    bf16x8 o;
    #pragma unroll
    for (int j = 0; j < 8; j++) o[j] = t[s8 + j][eloc + ee];
    *(bf16x8*)(dst + (size_t)(e0 + eloc + ee) * SS + s8) = o;
  }
}

// ---- one K=32 sub-step of MFMA from a k-major LDS tile:
// tile layout [kslot(4)][row(128)][8 shorts]; kslot = lane>>4.
// Lanes 0-15 read consecutive rows (16B stride) -> banks fully spread (conflict-free).
__device__ __forceinline__ void compute32(const short* As, const short* Bs,
                                          int wr, int wc, int lrow, int kg,
                                          f32x4 acc[4][4]) {
  bf16x8 af[4], bv[4];
  #pragma unroll
  for (int m = 0; m < 4; m++)
    af[m] = *(const bf16x8*)(As + kg + (wr*64 + m*16 + lrow) * 8);
  #pragma unroll
  for (int n = 0; n < 4; n++)
    bv[n] = *(const bf16x8*)(Bs + kg + (wc*64 + n*16 + lrow) * 8);
  #pragma unroll
  for (int m = 0; m < 4; m++)
    #pragma unroll
    for (int n = 0; n < 4; n++)
      acc[m][n] = __builtin_amdgcn_mfma_f32_16x16x32_bf16(af[m], bv[n], acc[m][n], 0, 0, 0);
}

// ---- NT GEMM core, 2-phase prefetch (double-buffered LDS):
// C(128x128) = A(128xK, row-major lda) * B'(128xK, row-major ldb)^T
// 4 waves, each a 64x64 quadrant of 4x4 16x16x32 MFMA fragments.
// LDS: 16384 shorts = 32KB; [As0|Bs0|As1|Bs1] each 4096 shorts.
// Staging: thread tid loads row (tid&127), kslot (tid>>7) [+2 for 2nd call];
// dest = buf + tid*16B [+4KB] -> exactly k-major layout, lane-linear per wave.
__device__ __forceinline__ void gemm2ph(const short* __restrict__ A, int lda,
                                        const short* __restrict__ Bm, int ldb,
                                        int K, short* lds, f32x4 acc[4][4]) {
  int tid = threadIdx.x;
  int lane = tid & 63, wid = tid >> 6;
  int wr = wid >> 1, wc = wid & 1;
  int lrow = lane & 15, kg = (lane >> 4) * 1024;
  short* As0 = lds;
  short* Bs0 = lds + 4096;
  short* As1 = lds + 8192;
  short* Bs1 = lds + 12288;
  int row = tid & 127, ksl = tid >> 7;
  const short* gA0 = A + (size_t)row * lda + ksl * 8;
  const short* gA1 = gA0 + 16;
  const short* gB0 = Bm + (size_t)row * ldb + ksl * 8;
  const short* gB1 = gB0 + 16;

  #define STAGE(AS, BS, k0) do { \
    gld16(gA0 + (k0), (AS) + tid*8); \
    gld16(gA1 + (k0), (AS) + 2048 + tid*8); \
    gld16(gB0 + (k0), (BS) + tid*8); \
    gld16(gB1 + (k0), (BS) + 2048 + tid*8); \
  } while (0)

  STAGE(As0, Bs0, 0);
  asm volatile("s_waitcnt vmcnt(0)" ::: "memory");
  __syncthreads();
  int NT = K / 32;                 // always even here (16 or 96)
  for (int t = 0; t < NT; t += 2) {
    if (t + 1 < NT) STAGE(As1, Bs1, (t+1)*32);
    compute32(As0, Bs0, wr, wc, lrow, kg, acc);
    asm volatile("s_waitcnt vmcnt(0)" ::: "memory");
    __syncthreads();
    if (t + 1 < NT) {
      if (t + 2 < NT) STAGE(As0, Bs0, (t+2)*32);
      compute32(As1, Bs1, wr, wc, lrow, kg, acc);
      asm volatile("s_waitcnt vmcnt(0)" ::: "memory");
      __syncthreads();
    }
  }
  #undef STAGE
}

// ---- kA: AxpX[hb] = adj_hb @ X_{h,layer} + X   (bf16 out)
__global__ __launch_bounds__(256) void k_gemmA(
    const short* __restrict__ adjb, const short* __restrict__ xtp,
    const float* __restrict__ x0f, const short* __restrict__ finb,
    int layer, short* __restrict__ axpx) {
  __shared__ short lds[16384];
  int bx = xswz(HH*BB*16);
  int hb = bx >> 4, q = bx & 15;
  int h = hb / BB, b = hb % BB;
  int tr = q >> 2, tc = q & 3;
  const short* A = adjb + (size_t)hb * SS * SS + (size_t)(tr * 128) * SS;
  const short* Bm = (layer == 0)
      ? xtp + (size_t)b * DD * SS + (size_t)(tc * 128) * SS
      : xtp + (size_t)hb * DD * SS + (size_t)(tc * 128) * SS;
  f32x4 acc[4][4];
  #pragma unroll
  for (int m = 0; m < 4; m++)
    #pragma unroll
    for (int n = 0; n < 4; n++) acc[m][n] = (f32x4){0.f, 0.f, 0.f, 0.f};
  gemm2ph(A, SS, Bm, SS, SS, lds, acc);
  int lane = threadIdx.x & 63, wid = threadIdx.x >> 6;
  int wr = wid >> 1, wc = wid & 1;
  int r4 = (lane >> 4) * 4, cn = lane & 15;
  short* outp = axpx + (size_t)hb * SS * DD;
  #pragma unroll
  for (int m = 0; m < 4; m++) {
    #pragma unroll
    for (int n = 0; n < 4; n++) {
      #pragma unroll
      for (int r = 0; r < 4; r++) {
        int s = tr*128 + wr*64 + m*16 + r4 + r;
        int d = tc*128 + wc*64 + n*16 + cn;
        float add = (layer == 0)
            ? x0f[((size_t)b * SS + s) * DD + d]
            : b2f(finb[((size_t)b * SS + s) * FF + (size_t)(h * LL) * DD + d]);
        outp[(size_t)s * DD + d] = f2b(acc[m][n][r] + add);
      }
    }
  }
}

// ---- kB: Y = relu((AxpX @ W^T + 2b) * rdenom) -> final slab (bf16)
__global__ __launch_bounds__(256) void k_gemmB(
    const short* __restrict__ axpx, const short* __restrict__ wgb,
    const float* __restrict__ bg, const float* __restrict__ rden,
    int layer, short* __restrict__ finb) {
  __shared__ short lds[16384];
  int bx = xswz(HH*BB*16);
  int hb = bx >> 4, q = bx & 15;
  int h = hb / BB, b = hb % BB;
  int tr = q >> 2, tc = q & 3;
  int idx = h * LL + layer;
  const short* A = axpx + (size_t)hb * SS * DD + (size_t)(tr * 128) * DD;
  const short* Bm = wgb + (size_t)idx * DD * DD + (size_t)(tc * 128) * DD;
  f32x4 acc[4][4];
  #pragma unroll
  for (int m = 0; m < 4; m++)
    #pragma unroll
    for (int n = 0; n < 4; n++) acc[m][n] = (f32x4){0.f, 0.f, 0.f, 0.f};
  gemm2ph(A, DD, Bm, DD, DD, lds, acc);
  int lane = threadIdx.x & 63, wid = threadIdx.x >> 6;
  int wr = wid >> 1, wc = wid & 1;
  int r4 = (lane >> 4) * 4, cn = lane & 15;
  #pragma unroll
  for (int m = 0; m < 4; m++) {
    #pragma unroll
    for (int n = 0; n < 4; n++) {
      #pragma unroll
      for (int r = 0; r < 4; r++) {
        int s = tr*128 + wr*64 + m*16 + r4 + r;
        int e = tc*128 + wc*64 + n*16 + cn;
        float v = (acc[m][n][r] + 2.0f * bg[(size_t)idx * DD + e])
                  * rden[(size_t)hb * SS + s];
        v = fmaxf(v, 0.0f);
        finb[((size_t)b * SS + s) * FF + (size_t)idx * DD + e] = f2b(v);
      }
    }
  }
}

// ---- kF: out = gcn_inputs + final @ W_out^T + b_out  (fp32 out)
__global__ __launch_bounds__(256) void k_gemmF(
    const short* __restrict__ finb, const short* __restrict__ wob,
    const float* __restrict__ bo, const float* __restrict__ x0f,
    float* __restrict__ out) {
  __shared__ short lds[16384];
  int bx = xswz(BB*16);
  int b = bx >> 4, q = bx & 15;
  int tr = q >> 2, tc = q & 3;
  const short* A = finb + (size_t)b * SS * FF + (size_t)(tr * 128) * FF;
  const short* Bm = wob + (size_t)(tc * 128) * FF;
  f32x4 acc[4][4];
  #pragma unroll
  for (int m = 0; m < 4; m++)
    #pragma unroll
    for (int n = 0; n < 4; n++) acc[m][n] = (f32x4){0.f, 0.f, 0.f, 0.f};
  gemm2ph(A, FF, Bm, FF, FF, lds, acc);
  int lane = threadIdx.x & 63, wid = threadIdx.x >> 6;
  int wr = wid >> 1, wc = wid & 1;
  int r4 = (lane >> 4) * 4, cn = lane & 15;
  #pragma unroll
  for (int m = 0; m < 4; m++) {
    #pragma unroll
    for (int n = 0; n < 4; n++) {
      #pragma unroll
      for (int r = 0; r < 4; r++) {
        int s = tr*128 + wr*64 + m*16 + r4 + r;
        int d = tc*128 + wc*64 + n*16 + cn;
        size_t o = ((size_t)b * SS + s) * DD + d;
        out[o] = acc[m][n][r] + bo[d] + x0f[o];
      }
    }
  }
}

extern "C" void kernel_launch(void* const* d_in, const int* in_sizes, int n_in,
                              void* d_out, int out_size, void* d_ws, size_t ws_size,
                              hipStream_t stream) {
  const float* adj = (const float*)d_in[0];
  const float* x0  = (const float*)d_in[1];
  // d_in[2], d_in[3]: mask / domain_mask — unused by the reference forward.
  const float* wg  = (const float*)d_in[4];
  const float* bg  = (const float*)d_in[5];
  const float* wo  = (const float*)d_in[6];
  const float* bo  = (const float*)d_in[7];
  float* out = (float*)d_out;

  char* p = (char*)d_ws;
  short* adjb = (short*)p; p += (size_t)HH*BB*SS*SS*2;   // 25,165,824
  short* x0t  = (short*)p; p += (size_t)BB*DD*SS*2;      //  8,388,608
  short* yt   = (short*)p; p += (size_t)HH*BB*DD*SS*2;   // 25,165,824
  short* axpx = (short*)p; p += (size_t)HH*BB*SS*DD*2;   // 25,165,824
  short* finb = (short*)p; p += (size_t)BB*SS*FF*2;      // 50,331,648
  short* wgb  = (short*)p; p += (size_t)HH*LL*DD*DD*2;   //  3,145,728
  short* wob  = (short*)p; p += (size_t)DD*FF*2;         //  3,145,728
  float* rden = (float*)p;                               //     98,304
  // total ~134.1 MiB of ws

  k_cvt_adj<<<HH*BB*SS/4, 256, 0, stream>>>(adj, adjb, rden);
  k_cvt_w<<<768, 256, 0, stream>>>(wg, wo, wgb, wob);
  k_t_x0<<<BB*64, 256, 0, stream>>>(x0, x0t);

  // layer 0
  k_gemmA<<<HH*BB*16, 256, 0, stream>>>(adjb, x0t, x0, finb, 0, axpx);
  k_gemmB<<<HH*BB*16, 256, 0, stream>>>(axpx, wgb, bg, rden, 0, finb);
  // transpose layer-0 outputs for layer-1 A-operand
  k_t_y<<<HH*BB*64, 256, 0, stream>>>(finb, yt);
  // layer 1
  k_gemmA<<<HH*BB*16, 256, 0, stream>>>(adjb, yt, x0, finb, 1, axpx);
  k_gemmB<<<HH*BB*16, 256, 0, stream>>>(axpx, wgb, bg, rden, 1, finb);
  // output projection + residual
  k_gemmF<<<BB*16, 256, 0, stream>>>(finb, wob, bo, x0, out);
}

// Round 3
// 216.829 us; speedup vs baseline: 1.2952x; 1.2952x over previous
//
#include <hip/hip_runtime.h>
#include <hip/hip_bf16.h>
#include <stdint.h>

// MultiGraphConvLayer: H=3 heads, L=2 layers, B=16, S=512, D=512.
// bf16 MFMA (16x16x32) GEMMs, fp32 accumulate.
// Round 3: coalesced staging + XOR slot-swizzle (conflict-free ds_read),
//          2-phase prefetch, split-K=4 gemmF + fused reduce, T1 XCD swizzle.

#define HH 3
#define LL 2
#define BB 16
#define SS 512
#define DD 512
#define FF 3072  // HH*LL*DD

typedef __attribute__((ext_vector_type(8))) short bf16x8;
typedef __attribute__((ext_vector_type(4))) float f32x4;
typedef __attribute__((ext_vector_type(4))) float vfloat4;

__device__ __forceinline__ short f2b(float x) {
  union { float f; uint32_t u; } v; v.f = x;
  return (short)((v.u + 0x7FFFu + ((v.u >> 16) & 1u)) >> 16);
}
__device__ __forceinline__ float b2f(short s) {
  union { uint32_t u; float f; } v; v.u = ((uint32_t)(uint16_t)s) << 16;
  return v.f;
}

__device__ __forceinline__ void gld16(const short* g, short* l) {
  __builtin_amdgcn_global_load_lds((const __attribute__((address_space(1))) void*)g,
                                   (__attribute__((address_space(3))) void*)l, 16, 0, 0);
}

// T1: XCD-chunked blockIdx swizzle (grid divisible by 8 — all ours are).
__device__ __forceinline__ int xswz(int grid) {
  int cpx = grid >> 3;
  return (blockIdx.x & 7) * cpx + (blockIdx.x >> 3);
}

// ---- adj fp32 -> bf16, plus rdenom = 1/(rowsum+1). One wave per row of 512.
__global__ void k_cvt_adj(const float* __restrict__ adj, short* __restrict__ adjb,
                          float* __restrict__ rden) {
  int row = blockIdx.x * 4 + (threadIdx.x >> 6);
  int lane = threadIdx.x & 63;
  const float* src = adj + (size_t)row * SS;
  vfloat4 a = *(const vfloat4*)(src + lane * 8);
  vfloat4 b = *(const vfloat4*)(src + lane * 8 + 4);
  bf16x8 o;
  o[0] = f2b(a[0]); o[1] = f2b(a[1]); o[2] = f2b(a[2]); o[3] = f2b(a[3]);
  o[4] = f2b(b[0]); o[5] = f2b(b[1]); o[6] = f2b(b[2]); o[7] = f2b(b[3]);
  *(bf16x8*)(adjb + (size_t)row * SS + lane * 8) = o;
  float s = a[0]+a[1]+a[2]+a[3]+b[0]+b[1]+b[2]+b[3];
  #pragma unroll
  for (int off = 32; off > 0; off >>= 1) s += __shfl_xor(s, off);
  if (lane == 0) rden[row] = 1.0f / (s + 1.0f);
}

// ---- W_gcn and W_out fp32 -> bf16 (both are 1,572,864 elements).
__global__ void k_cvt_w(const float* __restrict__ wg, const float* __restrict__ wo,
                        short* __restrict__ wgb, short* __restrict__ wob) {
  size_t i = ((size_t)blockIdx.x * 256 + threadIdx.x) * 8;
  vfloat4 a = *(const vfloat4*)(wg + i);
  vfloat4 b = *(const vfloat4*)(wg + i + 4);
  bf16x8 o;
  o[0]=f2b(a[0]); o[1]=f2b(a[1]); o[2]=f2b(a[2]); o[3]=f2b(a[3]);
  o[4]=f2b(b[0]); o[5]=f2b(b[1]); o[6]=f2b(b[2]); o[7]=f2b(b[3]);
  *(bf16x8*)(wgb + i) = o;
  a = *(const vfloat4*)(wo + i);
  b = *(const vfloat4*)(wo + i + 4);
  o[0]=f2b(a[0]); o[1]=f2b(a[1]); o[2]=f2b(a[2]); o[3]=f2b(a[3]);
  o[4]=f2b(b[0]); o[5]=f2b(b[1]); o[6]=f2b(b[2]); o[7]=f2b(b[3]);
  *(bf16x8*)(wob + i) = o;
}

// ---- gcn_inputs [B][S][D] fp32 -> X0T [B][D][S] bf16 (64x64 LDS tile transpose)
__global__ void k_t_x0(const float* __restrict__ x, short* __restrict__ xt) {
  __shared__ short t[64][72];
  int bid = blockIdx.x;            // BB*64
  int b = bid >> 6, q = bid & 63;
  int s0 = (q >> 3) * 64, d0 = (q & 7) * 64;
  int tid = threadIdx.x;
  int r = tid >> 4, c4 = (tid & 15) * 4;
  const float* src = x + ((size_t)b * SS + s0) * DD + d0;
  #pragma unroll
  for (int rr = 0; rr < 64; rr += 16) {
    vfloat4 v = *(const vfloat4*)(src + (size_t)(r + rr) * DD + c4);
    t[r+rr][c4+0] = f2b(v[0]); t[r+rr][c4+1] = f2b(v[1]);
    t[r+rr][c4+2] = f2b(v[2]); t[r+rr][c4+3] = f2b(v[3]);
  }
  __syncthreads();
  int dloc = tid >> 3, s8 = (tid & 7) * 8;
  short* dst = xt + (size_t)b * DD * SS + s0;
  #pragma unroll
  for (int dd = 0; dd < 64; dd += 32) {
    bf16x8 o;
    #pragma unroll
    for (int j = 0; j < 8; j++) o[j] = t[s8 + j][dloc + dd];
    *(bf16x8*)(dst + (size_t)(d0 + dloc + dd) * SS + s8) = o;
  }
}

// ---- final slab (layer-0 outputs, bf16, row stride FF) -> YT [H*B][D][S] bf16
__global__ void k_t_y(const short* __restrict__ fin, short* __restrict__ yt) {
  __shared__ short t[64][72];
  int bid = blockIdx.x;            // HH*BB*64
  int hb = bid >> 6, q = bid & 63;
  int h = hb / BB, b = hb % BB;
  int s0 = (q >> 3) * 64, e0 = (q & 7) * 64;
  int tid = threadIdx.x;
  int r = tid >> 3, c8 = (tid & 7) * 8;
  const short* src = fin + ((size_t)b * SS + s0) * FF + (size_t)(h * LL) * DD + e0;
  #pragma unroll
  for (int rr = 0; rr < 64; rr += 32) {
    bf16x8 v = *(const bf16x8*)(src + (size_t)(r + rr) * FF + c8);
    #pragma unroll
    for (int j = 0; j < 8; j++) t[r+rr][c8+j] = v[j];
  }
  __syncthreads();
  int eloc = tid >> 3, s8 = (tid & 7) * 8;
  short* dst = yt + (size_t)hb * DD * SS + s0;
  #pragma unroll
  for (int ee = 0; ee < 64; ee += 32) {
    bf16x8 o;
    #pragma unroll
    for (int j = 0; j < 8; j++) o[j] = t[s8 + j][eloc + ee];
    *(bf16x8*)(dst + (size_t)(e0 + eloc + ee) * SS + s8) = o;
  }
}

// ---- one K=32 sub-step from a row-major [128][32] LDS tile with XOR-swizzled
// 16B slots: LDS (row, s) holds global (row, s ^ ((row>>1)&3)).
// Read: lane wants global slot (lane>>4) of row (.. + lane&15) ->
//   LDS slot = (lane>>4) ^ ((lane&15)>>1)&3  (per-lane constant kgs, in shorts).
// Within each 16-lane group: <=2-way bank aliasing (free).
__device__ __forceinline__ void compute32(const short* As, const short* Bs,
                                          int wr, int wc, int lrow, int kgs,
                                          f32x4 acc[4][4]) {
  bf16x8 af[4], bv[4];
  #pragma unroll
  for (int m = 0; m < 4; m++)
    af[m] = *(const bf16x8*)(As + (wr*64 + m*16 + lrow) * 32 + kgs);
  #pragma unroll
  for (int n = 0; n < 4; n++)
    bv[n] = *(const bf16x8*)(Bs + (wc*64 + n*16 + lrow) * 32 + kgs);
  #pragma unroll
  for (int m = 0; m < 4; m++)
    #pragma unroll
    for (int n = 0; n < 4; n++)
      acc[m][n] = __builtin_amdgcn_mfma_f32_16x16x32_bf16(af[m], bv[n], acc[m][n], 0, 0, 0);
}

// ---- NT GEMM core, 2-phase prefetch (double-buffered LDS):
// C(128x128) = A(128xK, row-major lda) * B'(128xK, row-major ldb)^T
// 4 waves, each a 64x64 quadrant of 4x4 16x16x32 MFMA fragments.
// Staging (coalesced): thread tid loads row tid>>2, 16B slot ((tid&3)^((tid>>3)&3))
// of the 64B K-chunk -> lanes 0..3 cover one 64B segment (permuted within).
// LDS dest is linear tid*16B (row-major [128][32] with swizzled slot content).
__device__ __forceinline__ void gemm2ph(const short* __restrict__ A, int lda,
                                        const short* __restrict__ Bm, int ldb,
                                        int K, short* lds, f32x4 acc[4][4]) {
  int tid = threadIdx.x;
  int lane = tid & 63, wid = tid >> 6;
  int wr = wid >> 1, wc = wid & 1;
  int lrow = lane & 15;
  int kgs = (((lane >> 4) ^ ((lane >> 1) & 3)) << 3);
  short* As0 = lds;
  short* Bs0 = lds + 4096;
  short* As1 = lds + 8192;
  short* Bs1 = lds + 12288;
  int gcol = (((tid & 3) ^ ((tid >> 3) & 3)) << 3);
  const short* ga = A + (size_t)(tid >> 2) * lda + gcol;
  const short* gb = Bm + (size_t)(tid >> 2) * ldb + gcol;

  #define STAGE(AS, BS, k0) do { \
    gld16(ga + (k0), (AS) + tid*8); \
    gld16(ga + (k0) + (size_t)64 * lda, (AS) + 2048 + tid*8); \
    gld16(gb + (k0), (BS) + tid*8); \
    gld16(gb + (k0) + (size_t)64 * ldb, (BS) + 2048 + tid*8); \
  } while (0)

  STAGE(As0, Bs0, 0);
  asm volatile("s_waitcnt vmcnt(0)" ::: "memory");
  __syncthreads();
  int NT = K / 32;                 // even everywhere here (16 or 24)
  for (int t = 0; t < NT; t += 2) {
    if (t + 1 < NT) STAGE(As1, Bs1, (t+1)*32);
    compute32(As0, Bs0, wr, wc, lrow, kgs, acc);
    asm volatile("s_waitcnt vmcnt(0)" ::: "memory");
    __syncthreads();
    if (t + 1 < NT) {
      if (t + 2 < NT) STAGE(As0, Bs0, (t+2)*32);
      compute32(As1, Bs1, wr, wc, lrow, kgs, acc);
      asm volatile("s_waitcnt vmcnt(0)" ::: "memory");
      __syncthreads();
    }
  }
  #undef STAGE
}

// ---- kA: AxpX[hb] = adj_hb @ X_{h,layer} + X   (bf16 out)
__global__ __launch_bounds__(256) void k_gemmA(
    const short* __restrict__ adjb, const short* __restrict__ xtp,
    const float* __restrict__ x0f, const short* __restrict__ finb,
    int layer, short* __restrict__ axpx) {
  __shared__ short lds[16384];
  int bx = xswz(HH*BB*16);
  int hb = bx >> 4, q = bx & 15;
  int h = hb / BB, b = hb % BB;
  int tr = q >> 2, tc = q & 3;
  const short* A = adjb + (size_t)hb * SS * SS + (size_t)(tr * 128) * SS;
  const short* Bm = (layer == 0)
      ? xtp + (size_t)b * DD * SS + (size_t)(tc * 128) * SS
      : xtp + (size_t)hb * DD * SS + (size_t)(tc * 128) * SS;
  f32x4 acc[4][4];
  #pragma unroll
  for (int m = 0; m < 4; m++)
    #pragma unroll
    for (int n = 0; n < 4; n++) acc[m][n] = (f32x4){0.f, 0.f, 0.f, 0.f};
  gemm2ph(A, SS, Bm, SS, SS, lds, acc);
  int lane = threadIdx.x & 63, wid = threadIdx.x >> 6;
  int wr = wid >> 1, wc = wid & 1;
  int r4 = (lane >> 4) * 4, cn = lane & 15;
  short* outp = axpx + (size_t)hb * SS * DD;
  #pragma unroll
  for (int m = 0; m < 4; m++) {
    #pragma unroll
    for (int n = 0; n < 4; n++) {
      #pragma unroll
      for (int r = 0; r < 4; r++) {
        int s = tr*128 + wr*64 + m*16 + r4 + r;
        int d = tc*128 + wc*64 + n*16 + cn;
        float add = (layer == 0)
            ? x0f[((size_t)b * SS + s) * DD + d]
            : b2f(finb[((size_t)b * SS + s) * FF + (size_t)(h * LL) * DD + d]);
        outp[(size_t)s * DD + d] = f2b(acc[m][n][r] + add);
      }
    }
  }
}

// ---- kB: Y = relu((AxpX @ W^T + 2b) * rdenom) -> final slab (bf16)
__global__ __launch_bounds__(256) void k_gemmB(
    const short* __restrict__ axpx, const short* __restrict__ wgb,
    const float* __restrict__ bg, const float* __restrict__ rden,
    int layer, short* __restrict__ finb) {
  __shared__ short lds[16384];
  int bx = xswz(HH*BB*16);
  int hb = bx >> 4, q = bx & 15;
  int h = hb / BB, b = hb % BB;
  int tr = q >> 2, tc = q & 3;
  int idx = h * LL + layer;
  const short* A = axpx + (size_t)hb * SS * DD + (size_t)(tr * 128) * DD;
  const short* Bm = wgb + (size_t)idx * DD * DD + (size_t)(tc * 128) * DD;
  f32x4 acc[4][4];
  #pragma unroll
  for (int m = 0; m < 4; m++)
    #pragma unroll
    for (int n = 0; n < 4; n++) acc[m][n] = (f32x4){0.f, 0.f, 0.f, 0.f};
  gemm2ph(A, DD, Bm, DD, DD, lds, acc);
  int lane = threadIdx.x & 63, wid = threadIdx.x >> 6;
  int wr = wid >> 1, wc = wid & 1;
  int r4 = (lane >> 4) * 4, cn = lane & 15;
  #pragma unroll
  for (int m = 0; m < 4; m++) {
    #pragma unroll
    for (int n = 0; n < 4; n++) {
      #pragma unroll
      for (int r = 0; r < 4; r++) {
        int s = tr*128 + wr*64 + m*16 + r4 + r;
        int e = tc*128 + wc*64 + n*16 + cn;
        float v = (acc[m][n][r] + 2.0f * bg[(size_t)idx * DD + e])
                  * rden[(size_t)hb * SS + s];
        v = fmaxf(v, 0.0f);
        finb[((size_t)b * SS + s) * FF + (size_t)idx * DD + e] = f2b(v);
      }
    }
  }
}

// ---- kF (split-K=4): part[ks] = final[:, ks*768:(ks+1)*768] @ W_out[:, same]^T
__global__ __launch_bounds__(256) void k_gemmF(
    const short* __restrict__ finb, const short* __restrict__ wob,
    float* __restrict__ part) {
  __shared__ short lds[16384];
  int bx = xswz(BB*16*4);          // 1024 blocks
  int ks = bx >> 8;                // 0..3
  int q = bx & 255;
  int tr = q >> 2, tc = q & 3;     // tr 0..63, tc 0..3
  const short* A = finb + (size_t)(tr * 128) * FF + ks * 768;
  const short* Bm = wob + (size_t)(tc * 128) * FF + ks * 768;
  f32x4 acc[4][4];
  #pragma unroll
  for (int m = 0; m < 4; m++)
    #pragma unroll
    for (int n = 0; n < 4; n++) acc[m][n] = (f32x4){0.f, 0.f, 0.f, 0.f};
  gemm2ph(A, FF, Bm, FF, 768, lds, acc);
  int lane = threadIdx.x & 63, wid = threadIdx.x >> 6;
  int wr = wid >> 1, wc = wid & 1;
  int r4 = (lane >> 4) * 4, cn = lane & 15;
  float* op = part + (size_t)ks * ((size_t)BB*SS*DD);
  #pragma unroll
  for (int m = 0; m < 4; m++) {
    #pragma unroll
    for (int n = 0; n < 4; n++) {
      #pragma unroll
      for (int r = 0; r < 4; r++) {
        int row = tr*128 + wr*64 + m*16 + r4 + r;
        int d = tc*128 + wc*64 + n*16 + cn;
        op[(size_t)row * DD + d] = acc[m][n][r];
      }
    }
  }
}

// ---- reduce: out = x0 + b_out + sum_ks part[ks]   (grid-stride, float4)
__global__ void k_redF(const float* __restrict__ part, const float* __restrict__ x0f,
                       const float* __restrict__ bo, float* __restrict__ out) {
  const size_t PSZ = (size_t)BB * SS * DD;          // 4,194,304
  const size_t NV = PSZ / 4;                        // float4 count
  for (size_t v = (size_t)blockIdx.x * 256 + threadIdx.x; v < NV;
       v += (size_t)gridDim.x * 256) {
    size_t i = v * 4;
    int d = (int)(i & (DD - 1));
    vfloat4 s = *(const vfloat4*)(part + i);
    s += *(const vfloat4*)(part + PSZ + i);
    s += *(const vfloat4*)(part + 2*PSZ + i);
    s += *(const vfloat4*)(part + 3*PSZ + i);
    s += *(const vfloat4*)(x0f + i);
    s += *(const vfloat4*)(bo + d);
    *(vfloat4*)(out + i) = s;
  }
}

extern "C" void kernel_launch(void* const* d_in, const int* in_sizes, int n_in,
                              void* d_out, int out_size, void* d_ws, size_t ws_size,
                              hipStream_t stream) {
  const float* adj = (const float*)d_in[0];
  const float* x0  = (const float*)d_in[1];
  // d_in[2], d_in[3]: mask / domain_mask — unused by the reference forward.
  const float* wg  = (const float*)d_in[4];
  const float* bg  = (const float*)d_in[5];
  const float* wo  = (const float*)d_in[6];
  const float* bo  = (const float*)d_in[7];
  float* out = (float*)d_out;

  char* p = (char*)d_ws;
  short* adjb = (short*)p; p += (size_t)HH*BB*SS*SS*2;   // 25,165,824
  short* x0t  = (short*)p; p += (size_t)BB*DD*SS*2;      //  8,388,608
  short* yt   = (short*)p; p += (size_t)HH*BB*DD*SS*2;   // 25,165,824
  short* axpx = (short*)p; p += (size_t)HH*BB*SS*DD*2;   // 25,165,824
  short* finb = (short*)p; p += (size_t)BB*SS*FF*2;      // 50,331,648
  short* wgb  = (short*)p; p += (size_t)HH*LL*DD*DD*2;   //  3,145,728
  short* wob  = (short*)p; p += (size_t)DD*FF*2;         //  3,145,728
  float* rden = (float*)p;                               //     98,304
  // split-K partials (64 MB) reuse adjb..axpx (83.9 MB), all dead by gemmF time
  float* part = (float*)d_ws;

  k_cvt_adj<<<HH*BB*SS/4, 256, 0, stream>>>(adj, adjb, rden);
  k_cvt_w<<<768, 256, 0, stream>>>(wg, wo, wgb, wob);
  k_t_x0<<<BB*64, 256, 0, stream>>>(x0, x0t);

  // layer 0
  k_gemmA<<<HH*BB*16, 256, 0, stream>>>(adjb, x0t, x0, finb, 0, axpx);
  k_gemmB<<<HH*BB*16, 256, 0, stream>>>(axpx, wgb, bg, rden, 0, finb);
  // transpose layer-0 outputs for layer-1 A-operand
  k_t_y<<<HH*BB*64, 256, 0, stream>>>(finb, yt);
  // layer 1
  k_gemmA<<<HH*BB*16, 256, 0, stream>>>(adjb, yt, x0, finb, 1, axpx);
  k_gemmB<<<HH*BB*16, 256, 0, stream>>>(axpx, wgb, bg, rden, 1, finb);
  // output projection (split-K=4) + fused reduce w/ bias + residual
  k_gemmF<<<BB*16*4, 256, 0, stream>>>(finb, wob, part);
  k_redF<<<2048, 256, 0, stream>>>(part, x0, bo, out);
}

// Round 4
// 216.138 us; speedup vs baseline: 1.2994x; 1.0032x over previous
//
#include <hip/hip_runtime.h>
#include <hip/hip_bf16.h>
#include <stdint.h>

// MultiGraphConvLayer: H=3 heads, L=2 layers, B=16, S=512, D=512.
// Round 4: 256x256 8-phase counted-vmcnt MFMA GEMM (T1+T2+T3+T4+T5),
//          gemmB epilogue fuses the transpose (k_t_y eliminated).

#define HH 3
#define LL 2
#define BB 16
#define SS 512
#define DD 512
#define FF 3072  // HH*LL*DD

typedef __attribute__((ext_vector_type(8))) short bf16x8;
typedef __attribute__((ext_vector_type(4))) float f32x4;
typedef __attribute__((ext_vector_type(4))) float vfloat4;
typedef __attribute__((ext_vector_type(4))) short shortx4;

__device__ __forceinline__ short f2b(float x) {
  union { float f; uint32_t u; } v; v.f = x;
  return (short)((v.u + 0x7FFFu + ((v.u >> 16) & 1u)) >> 16);
}
__device__ __forceinline__ float b2f(short s) {
  union { uint32_t u; float f; } v; v.u = ((uint32_t)(uint16_t)s) << 16;
  return v.f;
}

__device__ __forceinline__ void gld16(const short* g, short* l) {
  __builtin_amdgcn_global_load_lds((const __attribute__((address_space(1))) void*)g,
                                   (__attribute__((address_space(3))) void*)l, 16, 0, 0);
}

// T1: XCD-chunked blockIdx swizzle (grid divisible by 8 — all ours are).
__device__ __forceinline__ int xswz(int grid) {
  int cpx = grid >> 3;
  return (blockIdx.x & 7) * cpx + (blockIdx.x >> 3);
}

// ---- adj fp32 -> bf16, plus rdenom = 1/(rowsum+1). One wave per row of 512.
__global__ void k_cvt_adj(const float* __restrict__ adj, short* __restrict__ adjb,
                          float* __restrict__ rden) {
  int row = blockIdx.x * 4 + (threadIdx.x >> 6);
  int lane = threadIdx.x & 63;
  const float* src = adj + (size_t)row * SS;
  vfloat4 a = *(const vfloat4*)(src + lane * 8);
  vfloat4 b = *(const vfloat4*)(src + lane * 8 + 4);
  bf16x8 o;
  o[0] = f2b(a[0]); o[1] = f2b(a[1]); o[2] = f2b(a[2]); o[3] = f2b(a[3]);
  o[4] = f2b(b[0]); o[5] = f2b(b[1]); o[6] = f2b(b[2]); o[7] = f2b(b[3]);
  *(bf16x8*)(adjb + (size_t)row * SS + lane * 8) = o;
  float s = a[0]+a[1]+a[2]+a[3]+b[0]+b[1]+b[2]+b[3];
  #pragma unroll
  for (int off = 32; off > 0; off >>= 1) s += __shfl_xor(s, off);
  if (lane == 0) rden[row] = 1.0f / (s + 1.0f);
}

// ---- W_gcn and W_out fp32 -> bf16 (both 1,572,864 elements).
__global__ void k_cvt_w(const float* __restrict__ wg, const float* __restrict__ wo,
                        short* __restrict__ wgb, short* __restrict__ wob) {
  size_t i = ((size_t)blockIdx.x * 256 + threadIdx.x) * 8;
  vfloat4 a = *(const vfloat4*)(wg + i);
  vfloat4 b = *(const vfloat4*)(wg + i + 4);
  bf16x8 o;
  o[0]=f2b(a[0]); o[1]=f2b(a[1]); o[2]=f2b(a[2]); o[3]=f2b(a[3]);
  o[4]=f2b(b[0]); o[5]=f2b(b[1]); o[6]=f2b(b[2]); o[7]=f2b(b[3]);
  *(bf16x8*)(wgb + i) = o;
  a = *(const vfloat4*)(wo + i);
  b = *(const vfloat4*)(wo + i + 4);
  o[0]=f2b(a[0]); o[1]=f2b(a[1]); o[2]=f2b(a[2]); o[3]=f2b(a[3]);
  o[4]=f2b(b[0]); o[5]=f2b(b[1]); o[6]=f2b(b[2]); o[7]=f2b(b[3]);
  *(bf16x8*)(wob + i) = o;
}

// ---- gcn_inputs [B][S][D] fp32 -> X0T [B][D][S] bf16 (64x64 LDS transpose)
__global__ void k_t_x0(const float* __restrict__ x, short* __restrict__ xt) {
  __shared__ short t[64][72];
  int bid = blockIdx.x;            // BB*64
  int b = bid >> 6, q = bid & 63;
  int s0 = (q >> 3) * 64, d0 = (q & 7) * 64;
  int tid = threadIdx.x;
  int r = tid >> 4, c4 = (tid & 15) * 4;
  const float* src = x + ((size_t)b * SS + s0) * DD + d0;
  #pragma unroll
  for (int rr = 0; rr < 64; rr += 16) {
    vfloat4 v = *(const vfloat4*)(src + (size_t)(r + rr) * DD + c4);
    t[r+rr][c4+0] = f2b(v[0]); t[r+rr][c4+1] = f2b(v[1]);
    t[r+rr][c4+2] = f2b(v[2]); t[r+rr][c4+3] = f2b(v[3]);
  }
  __syncthreads();
  int dloc = tid >> 3, s8 = (tid & 7) * 8;
  short* dst = xt + (size_t)b * DD * SS + s0;
  #pragma unroll
  for (int dd = 0; dd < 64; dd += 32) {
    bf16x8 o;
    #pragma unroll
    for (int j = 0; j < 8; j++) o[j] = t[s8 + j][dloc + dd];
    *(bf16x8*)(dst + (size_t)(d0 + dloc + dd) * SS + s8) = o;
  }
}

// =====================================================================
// 256x256 8-phase GEMM core.  C = A(256 x K) * B'(256 x K)^T, NT = K/64.
// 8 waves = 2M x 4N; per-wave 128x64 output = acc[8][4] (16x16x32 frags).
// LDS (dynamic 128KB, shorts): buf b at b*32768:
//   [A-h0 8192][A-h1 8192][B-h0 8192][B-h1 8192], region = 128 rows x 64 cols,
//   16B slot s of row r holds global slot s^(r&7)  (involution swizzle).
// Schedule per iteration (tiles E=2j buf0, O=2j+1 buf1), 1 half-tile
// stage (2 gld16/thread) per phase, vmcnt(4) at ph4/ph8 only:
//  ph1 E(0,0) rdA0+rdB0 | st buf1.Ah0<-O     ph5 O(0,0) | st buf0.Ah0<-E2
//  ph2 E(0,1) rdB1      | st buf1.Ah1<-O     ph6 O(0,1) | st buf0.Ah1<-E2
//  ph3 E(1,1) rdA1      | st buf0.Bh0<-E2    ph7 O(1,1) | st buf1.Bh0<-O2
//  ph4 E(1,0) (regs)    | st buf0.Bh1<-E2 +VM  ph8 O(1,0)| st buf1.Bh1<-O2 +VM
// B frags (both n-halves) stay in regs -> B regions die after ph2/ph6;
// A regions die after ph3/ph7.  All ds_reads drained (lgkmcnt 0) BEFORE
// each barrier so stage-overwrites can never race in-flight reads.
// =====================================================================

#define FENCE_LG asm volatile("s_waitcnt lgkmcnt(0)" ::: "memory")
#define FENCE_VM4 asm volatile("s_waitcnt vmcnt(4) lgkmcnt(0)" ::: "memory")
#define BARR __builtin_amdgcn_s_barrier()

__device__ __forceinline__ void gemm256(const short* __restrict__ A, int lda,
                                        const short* __restrict__ Bm, int ldb,
                                        int NT, short* lds, f32x4 acc[8][4]) {
  const int tid = threadIdx.x;
  const int lane = tid & 63;
  const int wid = tid >> 6;
  const int wr = wid >> 2, wc = wid & 3;
  const int lr = lane & 15, lk = lane >> 4;
  const int sw0 = ((lk) ^ (lr & 7)) << 3;
  const int sw1 = ((4 + lk) ^ (lr & 7)) << 3;
  const short* pA0 = lds + wr * 8192 + lr * 64;
  const short* pA1 = pA0 + 32768;
  const short* pB0 = lds + 16384 + (wc >> 1) * 8192 + (wc & 1) * 4096 + lr * 64;
  const short* pB1 = pB0 + 32768;

  const int sr0 = tid >> 3;
  const int ssc = (((tid & 7) ^ (sr0 & 7)) << 3);
  const short* gA = A + (size_t)sr0 * lda + ssc;
  const short* gB = Bm + (size_t)sr0 * ldb + ssc;

#define ST_A(bufs, ah, kt) do { \
    const short* g_ = gA + (size_t)(ah) * 128 * lda + (kt) * 64; \
    short* d_ = lds + (bufs) + (ah) * 8192 + tid * 8; \
    gld16(g_, d_); gld16(g_ + (size_t)64 * lda, d_ + 4096); } while (0)
#define ST_B(bufs, bh, kt) do { \
    const short* g_ = gB + (size_t)(bh) * 128 * ldb + (kt) * 64; \
    short* d_ = lds + (bufs) + 16384 + (bh) * 8192 + tid * 8; \
    gld16(g_, d_); gld16(g_ + (size_t)64 * ldb, d_ + 4096); } while (0)

  bf16x8 av[4][2], bv[2][2][2];

#define READ_A(pAx, mh) do { \
    _Pragma("unroll") for (int mm = 0; mm < 4; mm++) { \
      av[mm][0] = *(const bf16x8*)((pAx) + (mh) * 4096 + mm * 1024 + sw0); \
      av[mm][1] = *(const bf16x8*)((pAx) + (mh) * 4096 + mm * 1024 + sw1); \
    } } while (0)
#define READ_B(pBx, nh) do { \
    _Pragma("unroll") for (int nn = 0; nn < 2; nn++) { \
      bv[nh][nn][0] = *(const bf16x8*)((pBx) + (nh) * 2048 + nn * 1024 + sw0); \
      bv[nh][nn][1] = *(const bf16x8*)((pBx) + (nh) * 2048 + nn * 1024 + sw1); \
    } } while (0)
#define QUAD(mh, nh) do { \
    __builtin_amdgcn_s_setprio(1); \
    _Pragma("unroll") for (int mm = 0; mm < 4; mm++) \
    _Pragma("unroll") for (int nn = 0; nn < 2; nn++) \
    _Pragma("unroll") for (int kk = 0; kk < 2; kk++) \
      acc[(mh)*4+mm][(nh)*2+nn] = __builtin_amdgcn_mfma_f32_16x16x32_bf16( \
          av[mm][kk], bv[nh][nn][kk], acc[(mh)*4+mm][(nh)*2+nn], 0, 0, 0); \
    __builtin_amdgcn_s_setprio(0); } while (0)

  // prologue: tile0 -> buf0 (all 4 halves), tile1 B -> buf1.
  ST_B(0, 0, 0); ST_B(0, 1, 0);
  ST_A(0, 0, 0); ST_A(0, 1, 0);
  ST_B(32768, 0, 1); ST_B(32768, 1, 1);
  FENCE_VM4;                       // 12 out -> oldest 8 (tile0) landed
  BARR;

  const int IT = NT >> 1;
  for (int j = 0; j < IT; j++) {
    int o = 2 * j + 1;
    int e2 = 2 * j + 2; if (e2 >= NT) e2 -= NT;
    int o2 = e2 + 1;
    // ph1
    READ_A(pA0, 0); READ_B(pB0, 0);
    ST_A(32768, 0, o);
    FENCE_LG; BARR;
    QUAD(0, 0);
    // ph2
    READ_B(pB0, 1);
    ST_A(32768, 1, o);
    FENCE_LG; BARR;
    QUAD(0, 1);
    // ph3
    READ_A(pA0, 1);
    ST_B(0, 0, e2);
    FENCE_LG; BARR;
    QUAD(1, 1);
    // ph4
    ST_B(0, 1, e2);
    FENCE_VM4; BARR;
    QUAD(1, 0);
    // ph5
    READ_A(pA1, 0); READ_B(pB1, 0);
    ST_A(0, 0, e2);
    FENCE_LG; BARR;
    QUAD(0, 0);
    // ph6
    READ_B(pB1, 1);
    ST_A(0, 1, e2);
    FENCE_LG; BARR;
    QUAD(0, 1);
    // ph7
    READ_A(pA1, 1);
    ST_B(32768, 0, o2);
    FENCE_LG; BARR;
    QUAD(1, 1);
    // ph8
    ST_B(32768, 1, o2);
    FENCE_VM4; BARR;
    QUAD(1, 0);
  }
#undef ST_A
#undef ST_B
#undef READ_A
#undef READ_B
#undef QUAD
}

// ---- kA: AxpX[hb] = adj_hb @ X_{h,layer} + X   (bf16 out)
__global__ __launch_bounds__(512, 2) void k2_gemmA(
    const short* __restrict__ adjb, const short* __restrict__ xtp,
    const float* __restrict__ x0f, const short* __restrict__ finb,
    int layer, short* __restrict__ axpx) {
  extern __shared__ short lds[];
  int bx = xswz(HH * BB * 4);
  int hb = bx >> 2, q = bx & 3;
  int h = hb / BB, b = hb % BB;
  int tr = q >> 1, tc = q & 1;
  const short* A = adjb + (size_t)hb * SS * SS + (size_t)(tr * 256) * SS;
  const short* Bm = (layer == 0)
      ? xtp + (size_t)b * DD * SS + (size_t)(tc * 256) * SS
      : xtp + (size_t)hb * DD * SS + (size_t)(tc * 256) * SS;
  f32x4 acc[8][4];
  #pragma unroll
  for (int m = 0; m < 8; m++)
    #pragma unroll
    for (int n = 0; n < 4; n++) acc[m][n] = (f32x4){0.f, 0.f, 0.f, 0.f};
  gemm256(A, SS, Bm, SS, SS / 64, lds, acc);
  int lane = threadIdx.x & 63, wid = threadIdx.x >> 6;
  int wr = wid >> 2, wc = wid & 3;
  int lr = lane & 15, lk = lane >> 4;
  short* outp = axpx + (size_t)hb * SS * DD;
  #pragma unroll
  for (int m = 0; m < 8; m++) {
    #pragma unroll
    for (int n = 0; n < 4; n++) {
      #pragma unroll
      for (int r = 0; r < 4; r++) {
        int s = tr * 256 + wr * 128 + m * 16 + lk * 4 + r;
        int d = tc * 256 + wc * 64 + n * 16 + lr;
        float add = (layer == 0)
            ? x0f[((size_t)b * SS + s) * DD + d]
            : b2f(finb[((size_t)b * SS + s) * FF + (size_t)(h * LL) * DD + d]);
        outp[(size_t)s * DD + d] = f2b(acc[m][n][r] + add);
      }
    }
  }
}

// ---- kB: Y = relu((AxpX @ W^T + 2b) * rdenom) -> finb; layer0 also -> yt^T
__global__ __launch_bounds__(512, 2) void k2_gemmB(
    const short* __restrict__ axpx, const short* __restrict__ wgb,
    const float* __restrict__ bg, const float* __restrict__ rden,
    int layer, short* __restrict__ finb, short* __restrict__ yt) {
  extern __shared__ short lds[];
  int bx = xswz(HH * BB * 4);
  int hb = bx >> 2, q = bx & 3;
  int h = hb / BB, b = hb % BB;
  int tr = q >> 1, tc = q & 1;
  int idx = h * LL + layer;
  const short* A = axpx + (size_t)hb * SS * DD + (size_t)(tr * 256) * DD;
  const short* Bm = wgb + (size_t)idx * DD * DD + (size_t)(tc * 256) * DD;
  f32x4 acc[8][4];
  #pragma unroll
  for (int m = 0; m < 8; m++)
    #pragma unroll
    for (int n = 0; n < 4; n++) acc[m][n] = (f32x4){0.f, 0.f, 0.f, 0.f};
  gemm256(A, DD, Bm, DD, DD / 64, lds, acc);
  int lane = threadIdx.x & 63, wid = threadIdx.x >> 6;
  int wr = wid >> 2, wc = wid & 3;
  int lr = lane & 15, lk = lane >> 4;
  #pragma unroll
  for (int m = 0; m < 8; m++) {
    #pragma unroll
    for (int n = 0; n < 4; n++) {
      shortx4 tp;
      #pragma unroll
      for (int r = 0; r < 4; r++) {
        int s = tr * 256 + wr * 128 + m * 16 + lk * 4 + r;
        int e = tc * 256 + wc * 64 + n * 16 + lr;
        float v = (acc[m][n][r] + 2.0f * bg[(size_t)idx * DD + e])
                  * rden[(size_t)hb * SS + s];
        v = fmaxf(v, 0.0f);
        short bw = f2b(v);
        finb[((size_t)b * SS + s) * FF + (size_t)idx * DD + e] = bw;
        tp[r] = bw;
      }
      if (layer == 0) {
        int sb = tr * 256 + wr * 128 + m * 16 + lk * 4;
        int e = tc * 256 + wc * 64 + n * 16 + lr;
        *(shortx4*)(yt + (size_t)hb * DD * SS + (size_t)e * SS + sb) = tp;
      }
    }
  }
}

// ---- kF (split-K=4): part[ks] = finb[:, ks*768+..] @ W_out[:, same]^T
__global__ __launch_bounds__(512, 2) void k2_gemmF(
    const short* __restrict__ finb, const short* __restrict__ wob,
    float* __restrict__ part) {
  extern __shared__ short lds[];
  int bx = xswz(256);
  int ks = bx >> 6, q = bx & 63;
  int tr = q >> 1, tc = q & 1;       // tr 0..31 over 8192 rows, tc 0..1
  const short* A = finb + (size_t)(tr * 256) * FF + ks * 768;
  const short* Bm = wob + (size_t)(tc * 256) * FF + ks * 768;
  f32x4 acc[8][4];
  #pragma unroll
  for (int m = 0; m < 8; m++)
    #pragma unroll
    for (int n = 0; n < 4; n++) acc[m][n] = (f32x4){0.f, 0.f, 0.f, 0.f};
  gemm256(A, FF, Bm, FF, 768 / 64, lds, acc);
  int lane = threadIdx.x & 63, wid = threadIdx.x >> 6;
  int wr = wid >> 2, wc = wid & 3;
  int lr = lane & 15, lk = lane >> 4;
  float* op = part + (size_t)ks * ((size_t)BB * SS * DD);
  #pragma unroll
  for (int m = 0; m < 8; m++) {
    #pragma unroll
    for (int n = 0; n < 4; n++) {
      #pragma unroll
      for (int r = 0; r < 4; r++) {
        int row = tr * 256 + wr * 128 + m * 16 + lk * 4 + r;
        int d = tc * 256 + wc * 64 + n * 16 + lr;
        op[(size_t)row * DD + d] = acc[m][n][r];
      }
    }
  }
}

// ---- reduce: out = x0 + b_out + sum_ks part[ks]   (grid-stride, float4)
__global__ void k_redF(const float* __restrict__ part, const float* __restrict__ x0f,
                       const float* __restrict__ bo, float* __restrict__ out) {
  const size_t PSZ = (size_t)BB * SS * DD;
  const size_t NV = PSZ / 4;
  for (size_t v = (size_t)blockIdx.x * 256 + threadIdx.x; v < NV;
       v += (size_t)gridDim.x * 256) {
    size_t i = v * 4;
    int d = (int)(i & (DD - 1));
    vfloat4 s = *(const vfloat4*)(part + i);
    s += *(const vfloat4*)(part + PSZ + i);
    s += *(const vfloat4*)(part + 2 * PSZ + i);
    s += *(const vfloat4*)(part + 3 * PSZ + i);
    s += *(const vfloat4*)(x0f + i);
    s += *(const vfloat4*)(bo + d);
    *(vfloat4*)(out + i) = s;
  }
}

extern "C" void kernel_launch(void* const* d_in, const int* in_sizes, int n_in,
                              void* d_out, int out_size, void* d_ws, size_t ws_size,
                              hipStream_t stream) {
  const float* adj = (const float*)d_in[0];
  const float* x0  = (const float*)d_in[1];
  // d_in[2], d_in[3]: mask / domain_mask — unused by the reference forward.
  const float* wg  = (const float*)d_in[4];
  const float* bg  = (const float*)d_in[5];
  const float* wo  = (const float*)d_in[6];
  const float* bo  = (const float*)d_in[7];
  float* out = (float*)d_out;

  char* p = (char*)d_ws;
  short* adjb = (short*)p; p += (size_t)HH*BB*SS*SS*2;   // 25,165,824
  short* x0t  = (short*)p; p += (size_t)BB*DD*SS*2;      //  8,388,608
  short* yt   = (short*)p; p += (size_t)HH*BB*DD*SS*2;   // 25,165,824
  short* axpx = (short*)p; p += (size_t)HH*BB*SS*DD*2;   // 25,165,824
  short* finb = (short*)p; p += (size_t)BB*SS*FF*2;      // 50,331,648
  short* wgb  = (short*)p; p += (size_t)HH*LL*DD*DD*2;   //  3,145,728
  short* wob  = (short*)p; p += (size_t)DD*FF*2;         //  3,145,728
  float* rden = (float*)p;                               //     98,304
  // split-K partials (64 MB) reuse adjb..axpx (83.9 MB) — dead by gemmF time
  float* part = (float*)d_ws;

  static int attr_done = 0;
  (void)attr_done;
  hipFuncSetAttribute((const void*)k2_gemmA,
                      hipFuncAttributeMaxDynamicSharedMemorySize, 131072);
  hipFuncSetAttribute((const void*)k2_gemmB,
                      hipFuncAttributeMaxDynamicSharedMemorySize, 131072);
  hipFuncSetAttribute((const void*)k2_gemmF,
                      hipFuncAttributeMaxDynamicSharedMemorySize, 131072);

  k_cvt_adj<<<HH*BB*SS/4, 256, 0, stream>>>(adj, adjb, rden);
  k_cvt_w<<<768, 256, 0, stream>>>(wg, wo, wgb, wob);
  k_t_x0<<<BB*64, 256, 0, stream>>>(x0, x0t);

  // layer 0
  k2_gemmA<<<HH*BB*4, 512, 131072, stream>>>(adjb, x0t, x0, finb, 0, axpx);
  k2_gemmB<<<HH*BB*4, 512, 131072, stream>>>(axpx, wgb, bg, rden, 0, finb, yt);
  // layer 1 (gemmB layer0 wrote yt = transposed layer-0 outputs)
  k2_gemmA<<<HH*BB*4, 512, 131072, stream>>>(adjb, yt, x0, finb, 1, axpx);
  k2_gemmB<<<HH*BB*4, 512, 131072, stream>>>(axpx, wgb, bg, rden, 1, finb, yt);
  // output projection (split-K=4) + fused reduce w/ bias + residual
  k2_gemmF<<<BB*16, 512, 131072, stream>>>(finb, wob, part);
  k_redF<<<2048, 256, 0, stream>>>(part, x0, bo, out);
}

// Round 5
// 192.858 us; speedup vs baseline: 1.4562x; 1.1207x over previous
//
#include <hip/hip_runtime.h>
#include <hip/hip_bf16.h>
#include <stdint.h>

// MultiGraphConvLayer: H=3 heads, L=2 layers, B=16, S=512, D=512.
// Round 5: proven 2-phase 128^2 MFMA GEMM + counted-vmcnt triple-buffer
// (raw s_barrier, vmcnt(4) steady-state), XOR slot swizzle (0 conflicts),
// T1 XCD swizzle, gemmB epilogue fuses yt transpose, split-K=4 gemmF.

#define HH 3
#define LL 2
#define BB 16
#define SS 512
#define DD 512
#define FF 3072  // HH*LL*DD

typedef __attribute__((ext_vector_type(8))) short bf16x8;
typedef __attribute__((ext_vector_type(4))) float f32x4;
typedef __attribute__((ext_vector_type(4))) float vfloat4;
typedef __attribute__((ext_vector_type(4))) short shortx4;

__device__ __forceinline__ short f2b(float x) {
  union { float f; uint32_t u; } v; v.f = x;
  return (short)((v.u + 0x7FFFu + ((v.u >> 16) & 1u)) >> 16);
}
__device__ __forceinline__ float b2f(short s) {
  union { uint32_t u; float f; } v; v.u = ((uint32_t)(uint16_t)s) << 16;
  return v.f;
}

__device__ __forceinline__ void gld16(const short* g, short* l) {
  __builtin_amdgcn_global_load_lds((const __attribute__((address_space(1))) void*)g,
                                   (__attribute__((address_space(3))) void*)l, 16, 0, 0);
}

// T1: XCD-chunked blockIdx swizzle (grid divisible by 8 — all ours are).
__device__ __forceinline__ int xswz(int grid) {
  int cpx = grid >> 3;
  return (blockIdx.x & 7) * cpx + (blockIdx.x >> 3);
}

// ---- adj fp32 -> bf16, plus rdenom = 1/(rowsum+1). One wave per row of 512.
__global__ void k_cvt_adj(const float* __restrict__ adj, short* __restrict__ adjb,
                          float* __restrict__ rden) {
  int row = blockIdx.x * 4 + (threadIdx.x >> 6);
  int lane = threadIdx.x & 63;
  const float* src = adj + (size_t)row * SS;
  vfloat4 a = *(const vfloat4*)(src + lane * 8);
  vfloat4 b = *(const vfloat4*)(src + lane * 8 + 4);
  bf16x8 o;
  o[0] = f2b(a[0]); o[1] = f2b(a[1]); o[2] = f2b(a[2]); o[3] = f2b(a[3]);
  o[4] = f2b(b[0]); o[5] = f2b(b[1]); o[6] = f2b(b[2]); o[7] = f2b(b[3]);
  *(bf16x8*)(adjb + (size_t)row * SS + lane * 8) = o;
  float s = a[0]+a[1]+a[2]+a[3]+b[0]+b[1]+b[2]+b[3];
  #pragma unroll
  for (int off = 32; off > 0; off >>= 1) s += __shfl_xor(s, off);
  if (lane == 0) rden[row] = 1.0f / (s + 1.0f);
}

// ---- W_gcn and W_out fp32 -> bf16 (both 1,572,864 elements).
__global__ void k_cvt_w(const float* __restrict__ wg, const float* __restrict__ wo,
                        short* __restrict__ wgb, short* __restrict__ wob) {
  size_t i = ((size_t)blockIdx.x * 256 + threadIdx.x) * 8;
  vfloat4 a = *(const vfloat4*)(wg + i);
  vfloat4 b = *(const vfloat4*)(wg + i + 4);
  bf16x8 o;
  o[0]=f2b(a[0]); o[1]=f2b(a[1]); o[2]=f2b(a[2]); o[3]=f2b(a[3]);
  o[4]=f2b(b[0]); o[5]=f2b(b[1]); o[6]=f2b(b[2]); o[7]=f2b(b[3]);
  *(bf16x8*)(wgb + i) = o;
  a = *(const vfloat4*)(wo + i);
  b = *(const vfloat4*)(wo + i + 4);
  o[0]=f2b(a[0]); o[1]=f2b(a[1]); o[2]=f2b(a[2]); o[3]=f2b(a[3]);
  o[4]=f2b(b[0]); o[5]=f2b(b[1]); o[6]=f2b(b[2]); o[7]=f2b(b[3]);
  *(bf16x8*)(wob + i) = o;
}

// ---- gcn_inputs [B][S][D] fp32 -> X0T [B][D][S] bf16 (64x64 LDS transpose)
__global__ void k_t_x0(const float* __restrict__ x, short* __restrict__ xt) {
  __shared__ short t[64][72];
  int bid = blockIdx.x;            // BB*64
  int b = bid >> 6, q = bid & 63;
  int s0 = (q >> 3) * 64, d0 = (q & 7) * 64;
  int tid = threadIdx.x;
  int r = tid >> 4, c4 = (tid & 15) * 4;
  const float* src = x + ((size_t)b * SS + s0) * DD + d0;
  #pragma unroll
  for (int rr = 0; rr < 64; rr += 16) {
    vfloat4 v = *(const vfloat4*)(src + (size_t)(r + rr) * DD + c4);
    t[r+rr][c4+0] = f2b(v[0]); t[r+rr][c4+1] = f2b(v[1]);
    t[r+rr][c4+2] = f2b(v[2]); t[r+rr][c4+3] = f2b(v[3]);
  }
  __syncthreads();
  int dloc = tid >> 3, s8 = (tid & 7) * 8;
  short* dst = xt + (size_t)b * DD * SS + s0;
  #pragma unroll
  for (int dd = 0; dd < 64; dd += 32) {
    bf16x8 o;
    #pragma unroll
    for (int j = 0; j < 8; j++) o[j] = t[s8 + j][dloc + dd];
    *(bf16x8*)(dst + (size_t)(d0 + dloc + dd) * SS + s8) = o;
  }
}

// ---- one K=32 sub-step from a row-major [128][32] LDS tile with XOR-swizzled
// 16B slots: LDS (row, s) holds global (row, s ^ ((row>>1)&3)).
// Per-lane read slot kgs = (lane>>4) ^ ((lane&15)>>1)&3 -> <=2-way aliasing (free).
__device__ __forceinline__ void compute32(const short* As, const short* Bs,
                                          int wr, int wc, int lrow, int kgs,
                                          f32x4 acc[4][4]) {
  bf16x8 af[4], bv[4];
  #pragma unroll
  for (int m = 0; m < 4; m++)
    af[m] = *(const bf16x8*)(As + (wr*64 + m*16 + lrow) * 32 + kgs);
  #pragma unroll
  for (int n = 0; n < 4; n++)
    bv[n] = *(const bf16x8*)(Bs + (wc*64 + n*16 + lrow) * 32 + kgs);
  #pragma unroll
  for (int m = 0; m < 4; m++)
    #pragma unroll
    for (int n = 0; n < 4; n++)
      acc[m][n] = __builtin_amdgcn_mfma_f32_16x16x32_bf16(af[m], bv[n], acc[m][n], 0, 0, 0);
}

// ---- NT GEMM core: triple-buffered, counted-vmcnt, single raw barrier/K-step.
// C(128x128) = A(128xK, lda) * B'(128xK, ldb)^T; 4 waves, 64x64 each.
// LDS: 3 bufs x (As 4096 | Bs 4096) shorts = 48KB.
// Steady state: 8 loads in flight (tiles t,t+1); vmcnt(4) drains oldest 4
// (tile t) issued 2 K-steps earlier -> latency hidden; raw s_barrier (no
// implicit drain); sched_barrier(0) prevents LDS-read hoist (rule #18).
// Stage at iter t overwrites buf[(t+2)%3]=buf[(t-1)%3]: dead, since every
// wave finished its ds_reads of tile t-1 before arriving at this barrier.
__device__ __forceinline__ void gemm2ph(const short* __restrict__ A, int lda,
                                        const short* __restrict__ Bm, int ldb,
                                        int K, short* lds, f32x4 acc[4][4]) {
  int tid = threadIdx.x;
  int lane = tid & 63, wid = tid >> 6;
  int wr = wid >> 1, wc = wid & 1;
  int lrow = lane & 15;
  int kgs = (((lane >> 4) ^ ((lane >> 1) & 3)) << 3);
  int gcol = (((tid & 3) ^ ((tid >> 3) & 3)) << 3);
  const short* ga = A + (size_t)(tid >> 2) * lda + gcol;
  const short* gb = Bm + (size_t)(tid >> 2) * ldb + gcol;

  #define STAGE(BUF, k0) do { \
    short* as_ = (BUF); short* bs_ = (BUF) + 4096; \
    gld16(ga + (k0), as_ + tid*8); \
    gld16(ga + (k0) + (size_t)64 * lda, as_ + 2048 + tid*8); \
    gld16(gb + (k0), bs_ + tid*8); \
    gld16(gb + (k0) + (size_t)64 * ldb, bs_ + 2048 + tid*8); \
  } while (0)

  short* b0 = lds;
  short* b1 = lds + 8192;
  short* b2 = lds + 16384;
  int NT = K / 32;
  STAGE(b0, 0);
  STAGE(b1, 32);
  for (int t = 0; t < NT - 1; t++) {
    asm volatile("s_waitcnt vmcnt(4)" ::: "memory");
    __builtin_amdgcn_s_barrier();
    __builtin_amdgcn_sched_barrier(0);
    if (t + 2 < NT) STAGE(b2, (t + 2) * 32);
    compute32(b0, b0 + 4096, wr, wc, lrow, kgs, acc);
    short* tmp = b0; b0 = b1; b1 = b2; b2 = tmp;
  }
  asm volatile("s_waitcnt vmcnt(0)" ::: "memory");
  __builtin_amdgcn_s_barrier();
  __builtin_amdgcn_sched_barrier(0);
  compute32(b0, b0 + 4096, wr, wc, lrow, kgs, acc);
  #undef STAGE
}

// ---- kA: AxpX[hb] = adj_hb @ X_{h,layer} + X   (bf16 out)
__global__ __launch_bounds__(256, 3) void k_gemmA(
    const short* __restrict__ adjb, const short* __restrict__ xtp,
    const float* __restrict__ x0f, const short* __restrict__ finb,
    int layer, short* __restrict__ axpx) {
  __shared__ short lds[24576];
  int bx = xswz(HH*BB*16);
  int hb = bx >> 4, q = bx & 15;
  int h = hb / BB, b = hb % BB;
  int tr = q >> 2, tc = q & 3;
  const short* A = adjb + (size_t)hb * SS * SS + (size_t)(tr * 128) * SS;
  const short* Bm = (layer == 0)
      ? xtp + (size_t)b * DD * SS + (size_t)(tc * 128) * SS
      : xtp + (size_t)hb * DD * SS + (size_t)(tc * 128) * SS;
  f32x4 acc[4][4];
  #pragma unroll
  for (int m = 0; m < 4; m++)
    #pragma unroll
    for (int n = 0; n < 4; n++) acc[m][n] = (f32x4){0.f, 0.f, 0.f, 0.f};
  gemm2ph(A, SS, Bm, SS, SS, lds, acc);
  int lane = threadIdx.x & 63, wid = threadIdx.x >> 6;
  int wr = wid >> 1, wc = wid & 1;
  int r4 = (lane >> 4) * 4, cn = lane & 15;
  short* outp = axpx + (size_t)hb * SS * DD;
  #pragma unroll
  for (int m = 0; m < 4; m++) {
    #pragma unroll
    for (int n = 0; n < 4; n++) {
      #pragma unroll
      for (int r = 0; r < 4; r++) {
        int s = tr*128 + wr*64 + m*16 + r4 + r;
        int d = tc*128 + wc*64 + n*16 + cn;
        float add = (layer == 0)
            ? x0f[((size_t)b * SS + s) * DD + d]
            : b2f(finb[((size_t)b * SS + s) * FF + (size_t)(h * LL) * DD + d]);
        outp[(size_t)s * DD + d] = f2b(acc[m][n][r] + add);
      }
    }
  }
}

// ---- kB: Y = relu((AxpX @ W^T + 2b) * rdenom) -> finb; layer0 also -> yt^T
__global__ __launch_bounds__(256, 3) void k_gemmB(
    const short* __restrict__ axpx, const short* __restrict__ wgb,
    const float* __restrict__ bg, const float* __restrict__ rden,
    int layer, short* __restrict__ finb, short* __restrict__ yt) {
  __shared__ short lds[24576];
  int bx = xswz(HH*BB*16);
  int hb = bx >> 4, q = bx & 15;
  int h = hb / BB, b = hb % BB;
  int tr = q >> 2, tc = q & 3;
  int idx = h * LL + layer;
  const short* A = axpx + (size_t)hb * SS * DD + (size_t)(tr * 128) * DD;
  const short* Bm = wgb + (size_t)idx * DD * DD + (size_t)(tc * 128) * DD;
  f32x4 acc[4][4];
  #pragma unroll
  for (int m = 0; m < 4; m++)
    #pragma unroll
    for (int n = 0; n < 4; n++) acc[m][n] = (f32x4){0.f, 0.f, 0.f, 0.f};
  gemm2ph(A, DD, Bm, DD, DD, lds, acc);
  int lane = threadIdx.x & 63, wid = threadIdx.x >> 6;
  int wr = wid >> 1, wc = wid & 1;
  int r4 = (lane >> 4) * 4, cn = lane & 15;
  #pragma unroll
  for (int m = 0; m < 4; m++) {
    #pragma unroll
    for (int n = 0; n < 4; n++) {
      shortx4 tp;
      #pragma unroll
      for (int r = 0; r < 4; r++) {
        int s = tr*128 + wr*64 + m*16 + r4 + r;
        int e = tc*128 + wc*64 + n*16 + cn;
        float v = (acc[m][n][r] + 2.0f * bg[(size_t)idx * DD + e])
                  * rden[(size_t)hb * SS + s];
        v = fmaxf(v, 0.0f);
        short bw = f2b(v);
        finb[((size_t)b * SS + s) * FF + (size_t)idx * DD + e] = bw;
        tp[r] = bw;
      }
      if (layer == 0) {
        int sb = tr*128 + wr*64 + m*16 + r4;
        int e = tc*128 + wc*64 + n*16 + cn;
        *(shortx4*)(yt + (size_t)hb * DD * SS + (size_t)e * SS + sb) = tp;
      }
    }
  }
}

// ---- kF (split-K=4): part[ks] = finb[:, ks*768+..] @ W_out[:, same]^T
__global__ __launch_bounds__(256, 3) void k_gemmF(
    const short* __restrict__ finb, const short* __restrict__ wob,
    float* __restrict__ part) {
  __shared__ short lds[24576];
  int bx = xswz(BB*16*4);          // 1024 blocks
  int ks = bx >> 8;                // 0..3
  int q = bx & 255;
  int tr = q >> 2, tc = q & 3;     // tr 0..63, tc 0..3
  const short* A = finb + (size_t)(tr * 128) * FF + ks * 768;
  const short* Bm = wob + (size_t)(tc * 128) * FF + ks * 768;
  f32x4 acc[4][4];
  #pragma unroll
  for (int m = 0; m < 4; m++)
    #pragma unroll
    for (int n = 0; n < 4; n++) acc[m][n] = (f32x4){0.f, 0.f, 0.f, 0.f};
  gemm2ph(A, FF, Bm, FF, 768, lds, acc);
  int lane = threadIdx.x & 63, wid = threadIdx.x >> 6;
  int wr = wid >> 1, wc = wid & 1;
  int r4 = (lane >> 4) * 4, cn = lane & 15;
  float* op = part + (size_t)ks * ((size_t)BB*SS*DD);
  #pragma unroll
  for (int m = 0; m < 4; m++) {
    #pragma unroll
    for (int n = 0; n < 4; n++) {
      #pragma unroll
      for (int r = 0; r < 4; r++) {
        int row = tr*128 + wr*64 + m*16 + r4 + r;
        int d = tc*128 + wc*64 + n*16 + cn;
        op[(size_t)row * DD + d] = acc[m][n][r];
      }
    }
  }
}

// ---- reduce: out = x0 + b_out + sum_ks part[ks]   (grid-stride, float4)
__global__ void k_redF(const float* __restrict__ part, const float* __restrict__ x0f,
                       const float* __restrict__ bo, float* __restrict__ out) {
  const size_t PSZ = (size_t)BB * SS * DD;
  const size_t NV = PSZ / 4;
  for (size_t v = (size_t)blockIdx.x * 256 + threadIdx.x; v < NV;
       v += (size_t)gridDim.x * 256) {
    size_t i = v * 4;
    int d = (int)(i & (DD - 1));
    vfloat4 s = *(const vfloat4*)(part + i);
    s += *(const vfloat4*)(part + PSZ + i);
    s += *(const vfloat4*)(part + 2*PSZ + i);
    s += *(const vfloat4*)(part + 3*PSZ + i);
    s += *(const vfloat4*)(x0f + i);
    s += *(const vfloat4*)(bo + d);
    *(vfloat4*)(out + i) = s;
  }
}

extern "C" void kernel_launch(void* const* d_in, const int* in_sizes, int n_in,
                              void* d_out, int out_size, void* d_ws, size_t ws_size,
                              hipStream_t stream) {
  const float* adj = (const float*)d_in[0];
  const float* x0  = (const float*)d_in[1];
  // d_in[2], d_in[3]: mask / domain_mask — unused by the reference forward.
  const float* wg  = (const float*)d_in[4];
  const float* bg  = (const float*)d_in[5];
  const float* wo  = (const float*)d_in[6];
  const float* bo  = (const float*)d_in[7];
  float* out = (float*)d_out;

  char* p = (char*)d_ws;
  short* adjb = (short*)p; p += (size_t)HH*BB*SS*SS*2;   // 25,165,824
  short* x0t  = (short*)p; p += (size_t)BB*DD*SS*2;      //  8,388,608
  short* yt   = (short*)p; p += (size_t)HH*BB*DD*SS*2;   // 25,165,824
  short* axpx = (short*)p; p += (size_t)HH*BB*SS*DD*2;   // 25,165,824
  short* finb = (short*)p; p += (size_t)BB*SS*FF*2;      // 50,331,648
  short* wgb  = (short*)p; p += (size_t)HH*LL*DD*DD*2;   //  3,145,728
  short* wob  = (short*)p; p += (size_t)DD*FF*2;         //  3,145,728
  float* rden = (float*)p;                               //     98,304
  // split-K partials (64 MB) reuse adjb..axpx (83.9 MB) — dead by gemmF time
  float* part = (float*)d_ws;

  k_cvt_adj<<<HH*BB*SS/4, 256, 0, stream>>>(adj, adjb, rden);
  k_cvt_w<<<768, 256, 0, stream>>>(wg, wo, wgb, wob);
  k_t_x0<<<BB*64, 256, 0, stream>>>(x0, x0t);

  // layer 0
  k_gemmA<<<HH*BB*16, 256, 0, stream>>>(adjb, x0t, x0, finb, 0, axpx);
  k_gemmB<<<HH*BB*16, 256, 0, stream>>>(axpx, wgb, bg, rden, 0, finb, yt);
  // layer 1 (gemmB layer-0 epilogue wrote yt = transposed layer-0 outputs)
  k_gemmA<<<HH*BB*16, 256, 0, stream>>>(adjb, yt, x0, finb, 1, axpx);
  k_gemmB<<<HH*BB*16, 256, 0, stream>>>(axpx, wgb, bg, rden, 1, finb, yt);
  // output projection (split-K=4) + fused reduce w/ bias + residual
  k_gemmF<<<BB*16*4, 256, 0, stream>>>(finb, wob, part);
  k_redF<<<2048, 256, 0, stream>>>(part, x0, bo, out);
}